// Round 3
// baseline (2955.156 us; speedup 1.0000x reference)
//
#include <hip/hip_runtime.h>

// GCN user-tower forward: user_h = relu(A_hat @ W + b), A_hat = D^-1/2 (A+I) D^-1/2
// deg is computed from `row` only (matches reference: segment_sum(ones, row)).

constexpr int N_USERS = 100000;
constexpr int EMB = 64;

// --- 1. degree histogram (deg counts edges only; +1 self loop added later) ---
__global__ void count_deg_kernel(const int* __restrict__ row, int E,
                                 unsigned* __restrict__ deg) {
    int stride = gridDim.x * blockDim.x;
    for (int e = blockIdx.x * blockDim.x + threadIdx.x; e < E; e += stride) {
        atomicAdd(&deg[row[e]], 1u);
    }
}

// --- 2. deg_inv_sqrt ---
__global__ void dis_kernel(const unsigned* __restrict__ deg,
                           float* __restrict__ dis, int n) {
    int i = blockIdx.x * blockDim.x + threadIdx.x;
    if (i < n) dis[i] = rsqrtf((float)(deg[i] + 1u));
}

// --- 3. edge scatter: 16 threads per edge, float4 gather + 4 atomic adds ---
__global__ void scatter_kernel(const int* __restrict__ row,
                               const int* __restrict__ col,
                               const float* __restrict__ dis,
                               const float4* __restrict__ uw4,
                               float* __restrict__ out, long long total) {
    long long stride = (long long)gridDim.x * blockDim.x;
    for (long long t = (long long)blockIdx.x * blockDim.x + threadIdx.x;
         t < total; t += stride) {
        int e = (int)(t >> 4);
        int l = (int)(t & 15);
        int r = row[e];
        int c = col[e];
        float norm = dis[r] * dis[c];
        float4 w = uw4[(long long)c * 16 + l];
        float* dst = out + (long long)r * EMB + l * 4;
        atomicAdd(dst + 0, w.x * norm);
        atomicAdd(dst + 1, w.y * norm);
        atomicAdd(dst + 2, w.z * norm);
        atomicAdd(dst + 3, w.w * norm);
    }
}

// --- 4. self loop + bias + relu, in place on out ---
__global__ void finalize_kernel(const float* __restrict__ dis,
                                const float4* __restrict__ uw4,
                                const float4* __restrict__ bias4,
                                float4* __restrict__ out4, int n /* N*16 */) {
    int t = blockIdx.x * blockDim.x + threadIdx.x;
    if (t >= n) return;
    int node = t >> 4;
    int l = t & 15;
    float s = dis[node];
    float inv = s * s;  // 1/deg
    float4 w = uw4[t];
    float4 b = bias4[l];
    float4 a = out4[t];
    float4 v;
    v.x = fmaxf(a.x + w.x * inv + b.x, 0.f);
    v.y = fmaxf(a.y + w.y * inv + b.y, 0.f);
    v.z = fmaxf(a.z + w.z * inv + b.z, 0.f);
    v.w = fmaxf(a.w + w.w * inv + b.w, 0.f);
    out4[t] = v;
}

extern "C" void kernel_launch(void* const* d_in, const int* in_sizes, int n_in,
                              void* d_out, int out_size, void* d_ws, size_t ws_size,
                              hipStream_t stream) {
    const int E = in_sizes[0] / 2;
    const int* row = (const int*)d_in[0];
    const int* col = row + E;
    const float* user_weight = (const float*)d_in[1];
    const float* user_bias   = (const float*)d_in[2];
    const float* item_emb    = (const float*)d_in[3];
    float* out = (float*)d_out;

    // workspace layout: [0, N*4) deg u32, [N*4, N*8) dis f32
    unsigned* deg = (unsigned*)d_ws;
    float* dis = (float*)((char*)d_ws + (size_t)N_USERS * 4);

    // zero deg + user_h accumulator region (harness poisons with 0xAA)
    hipMemsetAsync(deg, 0, (size_t)N_USERS * 4, stream);
    hipMemsetAsync(out, 0, (size_t)N_USERS * EMB * 4, stream);

    // 1. degree histogram
    count_deg_kernel<<<2048, 256, 0, stream>>>(row, E, deg);

    // 2. deg_inv_sqrt
    dis_kernel<<<(N_USERS + 255) / 256, 256, 0, stream>>>(deg, dis, N_USERS);

    // 3. edge scatter
    long long total = (long long)E * 16;
    int blocks = (int)((total + 255) / 256);
    if (blocks > 16384) blocks = 16384;
    scatter_kernel<<<blocks, 256, 0, stream>>>(row, col, dis,
                                               (const float4*)user_weight, out, total);

    // 4. self loop + bias + relu
    int n4 = N_USERS * (EMB / 4);
    finalize_kernel<<<(n4 + 255) / 256, 256, 0, stream>>>(
        dis, (const float4*)user_weight, (const float4*)user_bias,
        (float4*)out, n4);

    // 5. item_embeddings pass-through
    hipMemcpyAsync(out + (size_t)N_USERS * EMB, item_emb,
                   (size_t)in_sizes[3] * sizeof(float),
                   hipMemcpyDeviceToDevice, stream);
}

// Round 8
// 572.673 us; speedup vs baseline: 5.1603x; 5.1603x over previous
//
#include <hip/hip_runtime.h>

// GCN user tower: user_h = relu(D^-1/2 (A+I) D^-1/2 @ W + b), then passthrough items.
// Strategy: scatter->gather via device-built CSR (perm list), no fp32 atomics.
// Scratch lives in the item half of d_out (dead until the final D2D copy).

constexpr int N_USERS = 100000;
constexpr int EMB = 64;
constexpr int SCAN_CHUNK = 1024;                                   // 256 thr * 4
constexpr int SCAN_BLOCKS = (N_USERS + SCAN_CHUNK - 1) / SCAN_CHUNK; // 98

// --- 1. degree histogram (edges only; +1 self loop folded into rsqrt) ---
__global__ void count_deg_kernel(const int* __restrict__ row, int E,
                                 unsigned* __restrict__ deg) {
    int stride = gridDim.x * blockDim.x;
    for (int e = blockIdx.x * blockDim.x + threadIdx.x; e < E; e += stride)
        atomicAdd(&deg[row[e]], 1u);
}

// --- 2. deg_inv_sqrt ---
__global__ void dis_kernel(const unsigned* __restrict__ deg,
                           float* __restrict__ dis, int n) {
    int i = blockIdx.x * blockDim.x + threadIdx.x;
    if (i < n) dis[i] = rsqrtf((float)(deg[i] + 1u));
}

// --- 3a. scan: per-block partial sums ---
__global__ void scan_partial_kernel(const unsigned* __restrict__ deg,
                                    unsigned* __restrict__ bsums, int n) {
    __shared__ unsigned wsum[4];
    int base = blockIdx.x * SCAN_CHUNK + threadIdx.x * 4;
    unsigned t = 0;
#pragma unroll
    for (int j = 0; j < 4; ++j) {
        int i = base + j;
        if (i < n) t += deg[i];
    }
    unsigned lane = threadIdx.x & 63, wv = threadIdx.x >> 6;
    unsigned v = t;
    for (int off = 32; off > 0; off >>= 1) v += __shfl_down(v, off, 64);
    if (lane == 0) wsum[wv] = v;
    __syncthreads();
    if (threadIdx.x == 0)
        bsums[blockIdx.x] = wsum[0] + wsum[1] + wsum[2] + wsum[3];
}

// --- 3b. scan of the 98 block sums (exclusive, in place), single block ---
__global__ void scan_sums_kernel(unsigned* __restrict__ bsums, int nb) {
    __shared__ unsigned tmp[128];
    int t = threadIdx.x;
    unsigned v = (t < nb) ? bsums[t] : 0u;
    tmp[t] = v;
    __syncthreads();
    for (int off = 1; off < 128; off <<= 1) {
        unsigned add = (t >= off) ? tmp[t - off] : 0u;
        __syncthreads();
        tmp[t] += add;
        __syncthreads();
    }
    if (t < nb) bsums[t] = tmp[t] - v;  // exclusive
}

// --- 3c. scan: final row_start + cursor ---
__global__ void scan_final_kernel(const unsigned* __restrict__ deg,
                                  const unsigned* __restrict__ bsums,
                                  unsigned* __restrict__ row_start,
                                  unsigned* __restrict__ cursor, int n) {
    __shared__ unsigned wsum[4];
    int base = blockIdx.x * SCAN_CHUNK + threadIdx.x * 4;
    unsigned vals[4], t = 0;
#pragma unroll
    for (int j = 0; j < 4; ++j) {
        int i = base + j;
        vals[j] = (i < n) ? deg[i] : 0u;
        t += vals[j];
    }
    unsigned lane = threadIdx.x & 63, wv = threadIdx.x >> 6;
    unsigned incl = t;
    for (int off = 1; off < 64; off <<= 1) {
        unsigned u = __shfl_up(incl, off, 64);
        if (lane >= (unsigned)off) incl += u;
    }
    if (lane == 63) wsum[wv] = incl;
    __syncthreads();
    unsigned woff = 0;
    for (unsigned w = 0; w < wv; ++w) woff += wsum[w];
    unsigned excl = bsums[blockIdx.x] + woff + (incl - t);
#pragma unroll
    for (int j = 0; j < 4; ++j) {
        int i = base + j;
        if (i < n) { row_start[i] = excl; cursor[i] = excl; excl += vals[j]; }
    }
}

// --- 4. bin edges into per-row buckets ---
__global__ void bin_kernel(const int* __restrict__ row, const int* __restrict__ col,
                           unsigned* __restrict__ cursor, unsigned* __restrict__ perm,
                           int E) {
    int stride = gridDim.x * blockDim.x;
    for (int e = blockIdx.x * blockDim.x + threadIdx.x; e < E; e += stride) {
        unsigned pos = atomicAdd(&cursor[row[e]], 1u);
        perm[pos] = (unsigned)col[e];
    }
}

// --- 5. gather + self loop + bias + relu, register accumulation ---
__global__ void gather_kernel(const unsigned* __restrict__ row_start,
                              const unsigned* __restrict__ deg,
                              const float* __restrict__ dis,
                              const unsigned* __restrict__ perm,
                              const float4* __restrict__ uw4,
                              const float4* __restrict__ bias4,
                              float4* __restrict__ out4) {
    int t = blockIdx.x * blockDim.x + threadIdx.x;
    int r = t >> 4;
    if (r >= N_USERS) return;
    int l = t & 15;
    unsigned s = row_start[r], d = deg[r];
    float4 acc = make_float4(0.f, 0.f, 0.f, 0.f);
    for (unsigned k = s; k < s + d; ++k) {
        unsigned c = perm[k];
        float dc = dis[c];
        float4 w = uw4[(size_t)c * 16 + l];
        acc.x = fmaf(w.x, dc, acc.x);
        acc.y = fmaf(w.y, dc, acc.y);
        acc.z = fmaf(w.z, dc, acc.z);
        acc.w = fmaf(w.w, dc, acc.w);
    }
    float dr = dis[r];
    float inv = dr * dr;  // 1/deg_total (self-loop norm)
    float4 ws = uw4[(size_t)r * 16 + l];
    float4 b = bias4[l];
    float4 o;
    o.x = fmaxf(fmaf(acc.x, dr, fmaf(ws.x, inv, b.x)), 0.f);
    o.y = fmaxf(fmaf(acc.y, dr, fmaf(ws.y, inv, b.y)), 0.f);
    o.z = fmaxf(fmaf(acc.z, dr, fmaf(ws.z, inv, b.z)), 0.f);
    o.w = fmaxf(fmaf(acc.w, dr, fmaf(ws.w, inv, b.w)), 0.f);
    out4[t] = o;
}

extern "C" void kernel_launch(void* const* d_in, const int* in_sizes, int n_in,
                              void* d_out, int out_size, void* d_ws, size_t ws_size,
                              hipStream_t stream) {
    const int E = in_sizes[0] / 2;
    const int* row = (const int*)d_in[0];
    const int* col = row + E;
    const float* user_weight = (const float*)d_in[1];
    const float* user_bias   = (const float*)d_in[2];
    const float* item_emb    = (const float*)d_in[3];
    float* out = (float*)d_out;
    float* item_out = out + (size_t)N_USERS * EMB;

    // Scratch layout inside the (currently dead) item half of d_out: 14.4 MB < 25.6 MB
    unsigned* perm      = (unsigned*)item_out;       // E u32      (12.8 MB)
    unsigned* deg       = perm + E;                  // N u32
    float*    dis       = (float*)(deg + N_USERS);   // N f32
    unsigned* row_start = (unsigned*)(dis + N_USERS);// N u32
    unsigned* cursor    = row_start + N_USERS;       // N u32
    unsigned* bsums     = cursor + N_USERS;          // 98 u32

    hipMemsetAsync(deg, 0, (size_t)N_USERS * 4, stream);

    count_deg_kernel<<<2048, 256, 0, stream>>>(row, E, deg);
    dis_kernel<<<(N_USERS + 255) / 256, 256, 0, stream>>>(deg, dis, N_USERS);
    scan_partial_kernel<<<SCAN_BLOCKS, 256, 0, stream>>>(deg, bsums, N_USERS);
    scan_sums_kernel<<<1, 128, 0, stream>>>(bsums, SCAN_BLOCKS);
    scan_final_kernel<<<SCAN_BLOCKS, 256, 0, stream>>>(deg, bsums, row_start, cursor, N_USERS);
    bin_kernel<<<2048, 256, 0, stream>>>(row, col, cursor, perm, E);

    int gblocks = (N_USERS * 16 + 255) / 256;
    gather_kernel<<<gblocks, 256, 0, stream>>>(row_start, deg, dis, perm,
                                               (const float4*)user_weight,
                                               (const float4*)user_bias,
                                               (float4*)out);

    // item_embeddings pass-through LAST (overwrites the scratch region)
    hipMemcpyAsync(item_out, item_emb, (size_t)in_sizes[3] * sizeof(float),
                   hipMemcpyDeviceToDevice, stream);
}